// Round 6
// baseline (183.445 us; speedup 1.0000x reference)
//
#include <hip/hip_runtime.h>

// CRF loss, B=1024, T=512, K=32 — chunked associative scan, transposed form.
//
// Phase 1 (crf_chunk): 8192 chunk-tasks (1024 seq x 8 chunks), FOUR per
// 256-thread block (wave-private LDS, no inter-wave sync) so occupancy hits
// 32 waves/CU (64-thread blocks cap at 16 wg/CU = 43%). Per chunk:
//   N <- (D_t E^T) N   via 4x mfma_16x16x32_bf16
// A = D_t E^T built in-reg (E^T f32 const, one exp(emit) scalar per row-half,
// truncation-pack), B = N from LDS (b128), C packed back as contiguous b64
// column segments. Renorm every 8 steps by element (0,0) via readfirstlane
// (no max-butterfly). emit+mask prefetched 2-deep. No barriers at all.
// Phase 2 (crf_combine): 8 serial matvecs per sequence + logsumexp - scores.

#define K32 32
#define Tt  512
#define NCH 8
#define CHL 64
#define WPB 4

typedef float  float4v __attribute__((ext_vector_type(4)));
typedef short  short8v __attribute__((ext_vector_type(8)));

#define SWZX(x, m) __int_as_float(__builtin_amdgcn_ds_swizzle(__float_as_int(x), ((m) << 10) | 0x1F))
#define SWZ0(x)    __int_as_float(__builtin_amdgcn_ds_swizzle(__float_as_int(x), 0x0000))

__device__ inline float bf2f(unsigned h) {
    return __uint_as_float(h << 16);
}
// pack two f32 -> bf16x2 dword by truncation
__device__ inline unsigned pack_trunc(float hi, float lo) {
    return __builtin_amdgcn_perm(__float_as_uint(hi), __float_as_uint(lo), 0x07060302u);
}

union F8 { unsigned u[4]; short8v v; };

// ---------------- Phase 1: per-chunk matrix product ----------------
__global__ __launch_bounds__(256) void crf_chunk(
    const int*   __restrict__ labels,
    const float* __restrict__ y_pred,
    const float* __restrict__ trans,
    const float* __restrict__ mask,
    unsigned*    __restrict__ wsMT,   // [8192][512] dwords: M^T row-major bf16x2
    float*       __restrict__ wsS,    // [8192] log-scale per chunk
    float*       __restrict__ wsSc)   // [8192] path-score per chunk
{
    __shared__ unsigned short shN[WPB][32 * 40];   // per-wave 32x32, stride 40 bf16

    const int lane = threadIdx.x & 63;
    const int wid  = threadIdx.x >> 6;
    const int task = blockIdx.x * WPB + wid;       // 0..8191
    const int n    = lane & 15;
    const int q    = lane >> 4;
    const int seq  = task >> 3;
    const int c    = task & 7;
    unsigned short* N = shN[wid];

    const float* yp  = y_pred + (size_t)seq * Tt * K32;
    const int*   lb  = labels + (size_t)seq * Tt;
    const float* mkp = mask   + (size_t)seq * Tt;

    // ---- chunk path score (parallel: 64 lanes <-> 64 timesteps) ----
    float sc;
    {
        const int t = c * CHL + lane;
        const int   lab0 = lb[t];
        const float mv0  = mkp[t];
        sc = yp[t * K32 + lab0] * mv0;
        if (t < Tt - 1) {
            sc += trans[lab0 * K32 + lb[t + 1]] * (mv0 * mkp[t + 1]);
        }
#pragma unroll
        for (int s = 1; s < 64; s <<= 1) sc += __shfl_xor(sc, s, 64);
    }

    // ---- constant A base: E^T[m=16I+n][k=q*8+j] * 2^-5 (f32) ----
    float Ef0[8], Ef1[8];
#pragma unroll
    for (int jj = 0; jj < 8; ++jj) {
        Ef0[jj] = __expf(trans[(q * 8 + jj) * K32 + n])      * 0.03125f;
        Ef1[jj] = __expf(trans[(q * 8 + jj) * K32 + 16 + n]) * 0.03125f;
    }

    // ---- N = I (wave-private; in-order DS pipe, no barrier) ----
    for (int idx = lane; idx < 1024; idx += 64) {
        const int r = idx >> 5, k = idx & 31;
        N[r * 40 + k] = (r == k) ? (unsigned short)0x3F80 : (unsigned short)0;
    }

    const int t0 = (c == 0) ? 1 : c * CHL;
    const int t1 = c * CHL + CHL - 1;

    float Slog    = 0.0f;
    int   applied = 0;

    // 2-deep prefetch of emit (cols n, 16+n) and mask
    float eA0 = yp[t0 * K32 + n],       eA1 = yp[t0 * K32 + 16 + n];
    float mA  = mkp[t0];
    float eB0 = yp[(t0 + 1) * K32 + n], eB1 = yp[(t0 + 1) * K32 + 16 + n];
    float mB  = mkp[t0 + 1];

    for (int t = t0; t <= t1; ++t) {
        const float y0 = eA0, y1 = eA1, mv = mA;
        eA0 = eB0; eA1 = eB1; mA = mB;
        const int tn = (t + 2 <= t1) ? (t + 2) : t1;
        eB0 = yp[tn * K32 + n]; eB1 = yp[tn * K32 + 16 + n]; mB = mkp[tn];

        if (mv != 0.0f) {                         // wave-uniform
            const float s0 = __expf(y0);
            const float s1 = __expf(y1);
            F8 A0, A1;
#pragma unroll
            for (int h = 0; h < 4; ++h) {
                A0.u[h] = pack_trunc(s0 * Ef0[2 * h + 1], s0 * Ef0[2 * h]);
                A1.u[h] = pack_trunc(s1 * Ef1[2 * h + 1], s1 * Ef1[2 * h]);
            }
            const short8v B0 = *(const short8v*)&N[n * 40 + q * 8];
            const short8v B1 = *(const short8v*)&N[(16 + n) * 40 + q * 8];

            float4v c00 = {0.f, 0.f, 0.f, 0.f}, c01 = {0.f, 0.f, 0.f, 0.f};
            float4v c10 = {0.f, 0.f, 0.f, 0.f}, c11 = {0.f, 0.f, 0.f, 0.f};
            c00 = __builtin_amdgcn_mfma_f32_16x16x32_bf16(A0.v, B0, c00, 0, 0, 0);
            c01 = __builtin_amdgcn_mfma_f32_16x16x32_bf16(A0.v, B1, c01, 0, 0, 0);
            c10 = __builtin_amdgcn_mfma_f32_16x16x32_bf16(A1.v, B0, c10, 0, 0, 0);
            c11 = __builtin_amdgcn_mfma_f32_16x16x32_bf16(A1.v, B1, c11, 0, 0, 0);

            if ((applied & 7) == 7) {             // element-(0,0) renorm
                const float cn = __uint_as_float(
                    __builtin_amdgcn_readfirstlane(__float_as_uint(c00[0])));
                const float rs = 1.0f / cn;
#pragma unroll
                for (int r = 0; r < 4; ++r) {
                    c00[r] *= rs; c01[r] *= rs; c10[r] *= rs; c11[r] *= rs;
                }
                Slog += __logf(cn);
            }
            ++applied;

            // write back: col = 16J+n, rows 16I + q*4 .. +3 (contiguous b64)
            uint2 w;
            w.x = pack_trunc(c00[1], c00[0]); w.y = pack_trunc(c00[3], c00[2]);
            *(uint2*)&N[n * 40 + q * 4] = w;
            w.x = pack_trunc(c01[1], c01[0]); w.y = pack_trunc(c01[3], c01[2]);
            *(uint2*)&N[(16 + n) * 40 + q * 4] = w;
            w.x = pack_trunc(c10[1], c10[0]); w.y = pack_trunc(c10[3], c10[2]);
            *(uint2*)&N[n * 40 + 16 + q * 4] = w;
            w.x = pack_trunc(c11[1], c11[0]); w.y = pack_trunc(c11[3], c11[2]);
            *(uint2*)&N[(16 + n) * 40 + 16 + q * 4] = w;
        }
    }

    // dump M^T row-major (same wave wrote it; in-order DS pipe)
    unsigned* md = wsMT + (size_t)task * 512;
    for (int idx = lane; idx < 512; idx += 64) {
        const int k = idx >> 4, d = idx & 15;
        const unsigned lo = N[(2 * d) * 40 + k];
        const unsigned hi = N[(2 * d + 1) * 40 + k];
        md[idx] = lo | (hi << 16);
    }
    if (lane == 0) {
        wsS[task]  = Slog + (float)applied * 3.46573590f;   // + applied*5*ln2
        wsSc[task] = sc;
    }
}

// ---------------- Phase 2: serial combine (LDS-staged) ----------------
__global__ __launch_bounds__(64) void crf_combine(
    const float*    __restrict__ y_pred,
    const unsigned* __restrict__ wsMT,
    const float*    __restrict__ wsS,
    const float*    __restrict__ wsSc,
    float*          __restrict__ out)
{
    __shared__ unsigned shA[16 * 32 * 20];        // 16 matrices, row stride 20 dwords
    __shared__ __align__(16) float sh_p[64];

    const int lane = threadIdx.x;
    const int half = lane >> 5;
    const int j    = lane & 31;
    const int seq  = blockIdx.x * 2 + half;

    const float* yp = y_pred + (size_t)seq * Tt * K32;

    // stage 16 matrices (2 seqs x 8 chunks), coalesced b128
    const uint4* src = (const uint4*)(wsMT + (size_t)blockIdx.x * 2 * NCH * 512);
    for (int g = lane; g < 2048; g += 64) {
        const uint4 v = src[g];
        const int fd  = g << 2;
        const int scm = fd >> 9;
        const int rem = fd & 511;
        const int k   = rem >> 4;
        const int d   = rem & 15;
        *(uint4*)&shA[scm * 640 + k * 20 + d] = v;
    }
    __syncthreads();

    const float a0 = yp[j];
    const float m0 = SWZ0(a0);
    float p = __expf(a0 - m0);
    float S = m0;
    float scs = 0.0f;
#pragma unroll
    for (int cc = 0; cc < NCH; ++cc) {
        S   += wsS[seq * NCH + cc];
        scs += wsSc[seq * NCH + cc];
    }

    const float4* e4 = (const float4*)&sh_p[half * K32];

    for (int cc = 0; cc < NCH; ++cc) {
        sh_p[lane] = p;
        const unsigned* row = &shA[(half * NCH + cc) * 640 + j * 20];  // M^T row j
        float acc = 0.0f, cn = 0.0f;
#pragma unroll
        for (int ib = 0; ib < 8; ++ib) {
            const float4 pv = e4[ib];
            if (ib == 0) cn = pv.x;
            const unsigned d0 = row[2 * ib];
            const unsigned d1 = row[2 * ib + 1];
            acc = fmaf(pv.x, bf2f(d0 & 0xFFFFu), acc);
            acc = fmaf(pv.y, bf2f(d0 >> 16),     acc);
            acc = fmaf(pv.z, bf2f(d1 & 0xFFFFu), acc);
            acc = fmaf(pv.w, bf2f(d1 >> 16),     acc);
        }
        const float r = 1.0f / cn;
        p = acc * r;
        S += __logf(cn);
    }

    float sp = p;
    sp += SWZX(sp, 1);
    sp += SWZX(sp, 2);
    sp += SWZX(sp, 4);
    sp += SWZX(sp, 8);
    sp += SWZX(sp, 16);

    if (j == 0) {
        out[seq] = S + __logf(sp) - scs;
    }
}

extern "C" void kernel_launch(void* const* d_in, const int* in_sizes, int n_in,
                              void* d_out, int out_size, void* d_ws, size_t ws_size,
                              hipStream_t stream) {
    const int*   labels = (const int*)  d_in[0];
    const float* y_pred = (const float*)d_in[1];
    const float* trans  = (const float*)d_in[2];
    const float* mask   = (const float*)d_in[3];
    float* out = (float*)d_out;

    // workspace carve: M^T (16 MB) | S (32 KB) | Sc (32 KB)
    unsigned* wsMT = (unsigned*)d_ws;
    float* wsS  = (float*)((char*)d_ws + (size_t)1024 * NCH * 512 * 4);
    float* wsSc = wsS + 1024 * NCH;

    crf_chunk<<<(1024 * NCH) / WPB, 64 * WPB, 0, stream>>>(labels, y_pred, trans, mask, wsMT, wsS, wsSc);
    crf_combine<<<512, 64, 0, stream>>>(y_pred, wsMT, wsS, wsSc, out);
}

// Round 7
// 180.811 us; speedup vs baseline: 1.0146x; 1.0146x over previous
//
#include <hip/hip_runtime.h>

// CRF loss, B=1024, T=512, K=32 — chunked associative scan, transposed form.
//
// Per chunk (wave-private, 8192 waves): N <- D_t (E^T N)
//   * E^T is a CONSTANT pre-packed bf16 A-operand (zero per-step A-prep)
//   * E^T·N via 4x mfma_16x16x32_bf16, B = N from LDS (b128, col-major)
//   * D_t applied as row-scale on C frags: 8 exp from two float4 emit loads
//     (rows q*4..+3 and 16+q*4..+3 are contiguous), 16 muls
//   * mask folded to a 64-bit ballot once per chunk -> per-step test is SALU
//   * renorm every 8 applied steps by element (0,0) via readfirstlane
//   * C packed (v_perm trunc) and written back as 4 contiguous b64 segments
// Phase 2 (crf_combine): 8 serial matvecs per sequence + logsumexp - scores.

#define K32 32
#define Tt  512
#define NCH 8
#define CHL 64

typedef float  float4v __attribute__((ext_vector_type(4)));
typedef short  short8v __attribute__((ext_vector_type(8)));

#define SWZX(x, m) __int_as_float(__builtin_amdgcn_ds_swizzle(__float_as_int(x), ((m) << 10) | 0x1F))
#define SWZ0(x)    __int_as_float(__builtin_amdgcn_ds_swizzle(__float_as_int(x), 0x0000))

__device__ inline float bf2f(unsigned h) {
    return __uint_as_float(h << 16);
}
// pack two f32 -> bf16x2 dword by truncation
__device__ inline unsigned pack_trunc(float hi, float lo) {
    return __builtin_amdgcn_perm(__float_as_uint(hi), __float_as_uint(lo), 0x07060302u);
}
// round-to-nearest-even bf16 (one-time constants only)
__device__ inline unsigned short f2bf_rne(float x) {
    unsigned u = __float_as_uint(x);
    return (unsigned short)((u + 0x7FFFu + ((u >> 16) & 1u)) >> 16);
}

union F8 { unsigned u[4]; short8v v; };

// ---------------- Phase 1: per-chunk matrix product ----------------
__global__ __launch_bounds__(64) void crf_chunk(
    const int*   __restrict__ labels,
    const float* __restrict__ y_pred,
    const float* __restrict__ trans,
    const float* __restrict__ mask,
    unsigned*    __restrict__ wsMT,   // [8192][512] dwords: M^T row-major bf16x2
    float*       __restrict__ wsS,    // [8192] log-scale per chunk
    float*       __restrict__ wsSc)   // [8192] path-score per chunk
{
    __shared__ unsigned short N[32 * 40];     // N[col*40 + row], bf16, stride 40

    const int lane = threadIdx.x;             // 0..63
    const int n    = lane & 15;
    const int q    = lane >> 4;
    const int seq  = blockIdx.x >> 3;
    const int c    = blockIdx.x & 7;

    const float* yp  = y_pred + (size_t)seq * Tt * K32;
    const int*   lb  = labels + (size_t)seq * Tt;
    const float* mkp = mask   + (size_t)seq * Tt;

    // ---- chunk path score (parallel: 64 lanes <-> 64 timesteps) ----
    float sc;
    float mlane;
    {
        const int t = c * CHL + lane;
        const int   lab0 = lb[t];
        mlane = mkp[t];
        sc = yp[t * K32 + lab0] * mlane;
        if (t < Tt - 1) {
            sc += trans[lab0 * K32 + lb[t + 1]] * (mlane * mkp[t + 1]);
        }
#pragma unroll
        for (int s = 1; s < 64; s <<= 1) sc += __shfl_xor(sc, s, 64);
    }

    // ---- mask -> 64-bit ballot (per-step test becomes SALU) ----
    const unsigned long long mbits = __ballot(mlane != 0.0f);

    // ---- constant A-frags: A[m][k] = E^T[m][k]*2^-5 = exp(trans[k][m])*2^-5 ----
    F8 AE0, AE1;
#pragma unroll
    for (int h = 0; h < 4; ++h) {
        const int k0 = q * 8 + 2 * h, k1 = k0 + 1;
        AE0.u[h] = ((unsigned)f2bf_rne(__expf(trans[k0 * K32 + n]) * 0.03125f)) |
                   (((unsigned)f2bf_rne(__expf(trans[k1 * K32 + n]) * 0.03125f)) << 16);
        AE1.u[h] = ((unsigned)f2bf_rne(__expf(trans[k0 * K32 + 16 + n]) * 0.03125f)) |
                   (((unsigned)f2bf_rne(__expf(trans[k1 * K32 + 16 + n]) * 0.03125f)) << 16);
    }

    // ---- N = I (wave-private; in-order DS pipe, no barrier) ----
    for (int idx = lane; idx < 1024; idx += 64) {
        const int r = idx >> 5, k = idx & 31;
        N[r * 40 + k] = (r == k) ? (unsigned short)0x3F80 : (unsigned short)0;
    }

    const int t0 = (c == 0) ? 1 : c * CHL;
    const int t1 = c * CHL + CHL - 1;

    float Slog    = 0.0f;
    int   applied = 0;

    // emit row-scale loads: rows q*4..+3 and 16+q*4..+3 (contiguous float4)
    const float4* ypr0 = (const float4*)(yp + q * 4);        // + t*8 float4s
    const float4* ypr1 = (const float4*)(yp + 16 + q * 4);

    // 2-deep prefetch
    float4 eA0 = ypr0[(size_t)t0 * 8],       eA1 = ypr1[(size_t)t0 * 8];
    float4 eB0 = ypr0[(size_t)(t0 + 1) * 8], eB1 = ypr1[(size_t)(t0 + 1) * 8];

    for (int t = t0; t <= t1; ++t) {
        const float4 e0 = eA0, e1 = eA1;
        eA0 = eB0; eA1 = eB1;
        const int tn = (t + 2 <= t1) ? (t + 2) : t1;
        eB0 = ypr0[(size_t)tn * 8]; eB1 = ypr1[(size_t)tn * 8];

        if ((mbits >> (t & 63)) & 1ull) {         // wave-uniform, SALU test
            const short8v B0 = *(const short8v*)&N[n * 40 + q * 8];
            const short8v B1 = *(const short8v*)&N[(16 + n) * 40 + q * 8];

            float4v c00 = {0.f, 0.f, 0.f, 0.f}, c01 = {0.f, 0.f, 0.f, 0.f};
            float4v c10 = {0.f, 0.f, 0.f, 0.f}, c11 = {0.f, 0.f, 0.f, 0.f};
            c00 = __builtin_amdgcn_mfma_f32_16x16x32_bf16(AE0.v, B0, c00, 0, 0, 0);
            c01 = __builtin_amdgcn_mfma_f32_16x16x32_bf16(AE0.v, B1, c01, 0, 0, 0);
            c10 = __builtin_amdgcn_mfma_f32_16x16x32_bf16(AE1.v, B0, c10, 0, 0, 0);
            c11 = __builtin_amdgcn_mfma_f32_16x16x32_bf16(AE1.v, B1, c11, 0, 0, 0);

            // D_t row-scale: rows q*4+r scale s_r, rows 16+q*4+r scale u_r
            const float s0 = __expf(e0.x), s1 = __expf(e0.y);
            const float s2 = __expf(e0.z), s3 = __expf(e0.w);
            const float u0 = __expf(e1.x), u1 = __expf(e1.y);
            const float u2 = __expf(e1.z), u3 = __expf(e1.w);
            c00[0] *= s0; c00[1] *= s1; c00[2] *= s2; c00[3] *= s3;
            c01[0] *= s0; c01[1] *= s1; c01[2] *= s2; c01[3] *= s3;
            c10[0] *= u0; c10[1] *= u1; c10[2] *= u2; c10[3] *= u3;
            c11[0] *= u0; c11[1] *= u1; c11[2] *= u2; c11[3] *= u3;

            if ((applied & 7) == 7) {             // element-(0,0) renorm
                const float cn = __uint_as_float(
                    __builtin_amdgcn_readfirstlane(__float_as_uint(c00[0])));
                const float rs = 1.0f / cn;
#pragma unroll
                for (int r = 0; r < 4; ++r) {
                    c00[r] *= rs; c01[r] *= rs; c10[r] *= rs; c11[r] *= rs;
                }
                Slog += __logf(cn);
            }
            ++applied;

            // write back: col = 16J+n, rows 16I + q*4 .. +3 (contiguous b64)
            uint2 w;
            w.x = pack_trunc(c00[1], c00[0]); w.y = pack_trunc(c00[3], c00[2]);
            *(uint2*)&N[n * 40 + q * 4] = w;
            w.x = pack_trunc(c01[1], c01[0]); w.y = pack_trunc(c01[3], c01[2]);
            *(uint2*)&N[(16 + n) * 40 + q * 4] = w;
            w.x = pack_trunc(c10[1], c10[0]); w.y = pack_trunc(c10[3], c10[2]);
            *(uint2*)&N[n * 40 + 16 + q * 4] = w;
            w.x = pack_trunc(c11[1], c11[0]); w.y = pack_trunc(c11[3], c11[2]);
            *(uint2*)&N[(16 + n) * 40 + 16 + q * 4] = w;
        }
    }

    // dump M^T row-major (same wave wrote it; in-order DS pipe)
    unsigned* md = wsMT + (size_t)blockIdx.x * 512;
    for (int idx = lane; idx < 512; idx += 64) {
        const int k = idx >> 4, d = idx & 15;
        const unsigned lo = N[(2 * d) * 40 + k];
        const unsigned hi = N[(2 * d + 1) * 40 + k];
        md[idx] = lo | (hi << 16);
    }
    if (lane == 0) {
        wsS[blockIdx.x]  = Slog + (float)applied * 3.46573590f;   // + applied*5*ln2
        wsSc[blockIdx.x] = sc;
    }
}

// ---------------- Phase 2: serial combine (LDS-staged) ----------------
__global__ __launch_bounds__(64) void crf_combine(
    const float*    __restrict__ y_pred,
    const unsigned* __restrict__ wsMT,
    const float*    __restrict__ wsS,
    const float*    __restrict__ wsSc,
    float*          __restrict__ out)
{
    __shared__ unsigned shA[16 * 32 * 20];        // 16 matrices, row stride 20 dwords
    __shared__ __align__(16) float sh_p[64];

    const int lane = threadIdx.x;
    const int half = lane >> 5;
    const int j    = lane & 31;
    const int seq  = blockIdx.x * 2 + half;

    const float* yp = y_pred + (size_t)seq * Tt * K32;

    // stage 16 matrices (2 seqs x 8 chunks), coalesced b128
    const uint4* src = (const uint4*)(wsMT + (size_t)blockIdx.x * 2 * NCH * 512);
    for (int g = lane; g < 2048; g += 64) {
        const uint4 v = src[g];
        const int fd  = g << 2;
        const int scm = fd >> 9;
        const int rem = fd & 511;
        const int k   = rem >> 4;
        const int d   = rem & 15;
        *(uint4*)&shA[scm * 640 + k * 20 + d] = v;
    }
    __syncthreads();

    const float a0 = yp[j];
    const float m0 = SWZ0(a0);
    float p = __expf(a0 - m0);
    float S = m0;
    float scs = 0.0f;
#pragma unroll
    for (int cc = 0; cc < NCH; ++cc) {
        S   += wsS[seq * NCH + cc];
        scs += wsSc[seq * NCH + cc];
    }

    const float4* e4 = (const float4*)&sh_p[half * K32];

    for (int cc = 0; cc < NCH; ++cc) {
        sh_p[lane] = p;
        const unsigned* row = &shA[(half * NCH + cc) * 640 + j * 20];  // M^T row j
        float acc = 0.0f, cn = 0.0f;
#pragma unroll
        for (int ib = 0; ib < 8; ++ib) {
            const float4 pv = e4[ib];
            if (ib == 0) cn = pv.x;
            const unsigned d0 = row[2 * ib];
            const unsigned d1 = row[2 * ib + 1];
            acc = fmaf(pv.x, bf2f(d0 & 0xFFFFu), acc);
            acc = fmaf(pv.y, bf2f(d0 >> 16),     acc);
            acc = fmaf(pv.z, bf2f(d1 & 0xFFFFu), acc);
            acc = fmaf(pv.w, bf2f(d1 >> 16),     acc);
        }
        const float r = 1.0f / cn;
        p = acc * r;
        S += __logf(cn);
    }

    float sp = p;
    sp += SWZX(sp, 1);
    sp += SWZX(sp, 2);
    sp += SWZX(sp, 4);
    sp += SWZX(sp, 8);
    sp += SWZX(sp, 16);

    if (j == 0) {
        out[seq] = S + __logf(sp) - scs;
    }
}

extern "C" void kernel_launch(void* const* d_in, const int* in_sizes, int n_in,
                              void* d_out, int out_size, void* d_ws, size_t ws_size,
                              hipStream_t stream) {
    const int*   labels = (const int*)  d_in[0];
    const float* y_pred = (const float*)d_in[1];
    const float* trans  = (const float*)d_in[2];
    const float* mask   = (const float*)d_in[3];
    float* out = (float*)d_out;

    // workspace carve: M^T (16 MB) | S (32 KB) | Sc (32 KB)
    unsigned* wsMT = (unsigned*)d_ws;
    float* wsS  = (float*)((char*)d_ws + (size_t)1024 * NCH * 512 * 4);
    float* wsSc = wsS + 1024 * NCH;

    crf_chunk<<<1024 * NCH, 64, 0, stream>>>(labels, y_pred, trans, mask, wsMT, wsS, wsSc);
    crf_combine<<<512, 64, 0, stream>>>(y_pred, wsMT, wsS, wsSc, out);
}

// Round 8
// 171.988 us; speedup vs baseline: 1.0666x; 1.0513x over previous
//
#include <hip/hip_runtime.h>

// CRF loss, B=1024, T=512, K=32 — chunked associative scan, register-resident.
//
// Per chunk (8192 waves): N <- D_t (E^T N), all in registers:
//   * contraction index k is PERMUTED (pi: slot q*8+j <-> orig row q*4+j /
//     16+q*4+j-4). A (= E^T, constant) is packed in pi-order; under pi the
//     next step's B-fragment IS the current lane's own C fragments ->
//     NO LDS and NO cross-lane ops in the serial loop.
//   * step = 4x mfma_16x16x32_bf16 + 8 exp + 16 scale muls + 8 v_perm packs
//   * mask folded to a 64-bit ballot (SALU test); chunk-0's t=0 handled by
//     clearing ballot bit 0 -> uniform 64-step loops, unroll-2 ping-pong
//   * renorm every 8 applied steps by element (0,0) via readfirstlane
//   * one LDS transpose at kernel end for the M^T dump (negligible)
// Phase 2 (crf_combine): 8 serial matvecs per sequence + logsumexp - scores.

#define K32 32
#define Tt  512
#define NCH 8
#define CHL 64

typedef float  float4v __attribute__((ext_vector_type(4)));
typedef short  short8v __attribute__((ext_vector_type(8)));

#define SWZX(x, m) __int_as_float(__builtin_amdgcn_ds_swizzle(__float_as_int(x), ((m) << 10) | 0x1F))
#define SWZ0(x)    __int_as_float(__builtin_amdgcn_ds_swizzle(__float_as_int(x), 0x0000))

__device__ inline float bf2f(unsigned h) {
    return __uint_as_float(h << 16);
}
// pack two f32 -> bf16x2 dword by truncation: low16 = hi16(lo), high16 = hi16(hi)
__device__ inline unsigned pack_trunc(float hi, float lo) {
    return __builtin_amdgcn_perm(__float_as_uint(hi), __float_as_uint(lo), 0x07060302u);
}
// round-to-nearest-even bf16 (one-time constants only)
__device__ inline unsigned short f2bf_rne(float x) {
    unsigned u = __float_as_uint(x);
    return (unsigned short)((u + 0x7FFFu + ((u >> 16) & 1u)) >> 16);
}

union F8 { unsigned u[4]; short8v v; };

// ---------------- Phase 1: per-chunk matrix product (register-resident) ----------------
__global__ __launch_bounds__(64) void crf_chunk(
    const int*   __restrict__ labels,
    const float* __restrict__ y_pred,
    const float* __restrict__ trans,
    const float* __restrict__ mask,
    unsigned*    __restrict__ wsMT,   // [8192][512] dwords: M^T row-major bf16x2
    float*       __restrict__ wsS,    // [8192] log-scale per chunk
    float*       __restrict__ wsSc)   // [8192] path-score per chunk
{
    __shared__ unsigned short Ncm[32 * 40];   // end-of-kernel transpose only

    const int lane = threadIdx.x;             // 0..63
    const int n    = lane & 15;
    const int q    = lane >> 4;
    const int seq  = blockIdx.x >> 3;
    const int c    = blockIdx.x & 7;

    const float* yp  = y_pred + (size_t)seq * Tt * K32;
    const int*   lb  = labels + (size_t)seq * Tt;
    const float* mkp = mask   + (size_t)seq * Tt;

    // ---- chunk path score (parallel: 64 lanes <-> 64 timesteps) ----
    float sc;
    float mlane;
    {
        const int t = c * CHL + lane;
        const int   lab0 = lb[t];
        mlane = mkp[t];
        sc = yp[t * K32 + lab0] * mlane;
        if (t < Tt - 1) {
            sc += trans[lab0 * K32 + lb[t + 1]] * (mlane * mkp[t + 1]);
        }
#pragma unroll
        for (int s = 1; s < 64; s <<= 1) sc += __shfl_xor(sc, s, 64);
    }

    // ---- mask ballot; chunk 0 skips t=0 via cleared bit ----
    unsigned long long mbits = __ballot(mlane != 0.0f);
    if (c == 0) mbits &= ~1ull;

    // ---- constant A in pi-k-order: slot q*8+j <-> orig k = q*4+j | 16+q*4+(j-4) ----
    F8 AE0, AE1;
#pragma unroll
    for (int h = 0; h < 4; ++h) {
        const int k0 = (h < 2) ? (q * 4 + 2 * h) : (16 + q * 4 + 2 * (h - 2));
        const int k1 = k0 + 1;
        AE0.u[h] = ((unsigned)f2bf_rne(__expf(trans[k0 * K32 + n]) * 0.03125f)) |
                   (((unsigned)f2bf_rne(__expf(trans[k1 * K32 + n]) * 0.03125f)) << 16);
        AE1.u[h] = ((unsigned)f2bf_rne(__expf(trans[k0 * K32 + 16 + n]) * 0.03125f)) |
                   (((unsigned)f2bf_rne(__expf(trans[k1 * K32 + 16 + n]) * 0.03125f)) << 16);
    }

    // ---- B = identity fragments (pi-order) ----
    F8 B0, B1;
#pragma unroll
    for (int h = 0; h < 4; ++h) {
        const int r0 = (h < 2) ? (q * 4 + 2 * h) : (16 + q * 4 + 2 * (h - 2));
        const int r1 = r0 + 1;
        unsigned w0 = 0, w1 = 0;
        if (r0 == n)      w0 |= 0x3F80u;
        if (r1 == n)      w0 |= 0x3F800000u;
        if (r0 == 16 + n) w1 |= 0x3F80u;
        if (r1 == 16 + n) w1 |= 0x3F800000u;
        B0.u[h] = w0;
        B1.u[h] = w1;
    }

    float Slog    = 0.0f;
    int   applied = 0;

    // emit row-scale: rows q*4..+3 and 16+q*4..+3 (contiguous float4 each)
    const float4* ypr0 = (const float4*)(yp + q * 4);        // index: t*8
    const float4* ypr1 = (const float4*)(yp + 16 + q * 4);

    const int tbase = c * CHL;
    const int tmax  = tbase + CHL - 1;

    float4 eA0 = ypr0[(size_t)tbase * 8],       eA1 = ypr1[(size_t)tbase * 8];
    float4 eB0 = ypr0[(size_t)(tbase + 1) * 8], eB1 = ypr1[(size_t)(tbase + 1) * 8];

    auto dostep = [&](int t, const float4& e0, const float4& e1) {
        if ((mbits >> (t & 63)) & 1ull) {         // wave-uniform SALU test
            float4v c00 = {0.f, 0.f, 0.f, 0.f}, c01 = {0.f, 0.f, 0.f, 0.f};
            float4v c10 = {0.f, 0.f, 0.f, 0.f}, c11 = {0.f, 0.f, 0.f, 0.f};
            c00 = __builtin_amdgcn_mfma_f32_16x16x32_bf16(AE0.v, B0.v, c00, 0, 0, 0);
            c01 = __builtin_amdgcn_mfma_f32_16x16x32_bf16(AE0.v, B1.v, c01, 0, 0, 0);
            c10 = __builtin_amdgcn_mfma_f32_16x16x32_bf16(AE1.v, B0.v, c10, 0, 0, 0);
            c11 = __builtin_amdgcn_mfma_f32_16x16x32_bf16(AE1.v, B1.v, c11, 0, 0, 0);

            // D_t row-scale
            const float s0 = __expf(e0.x), s1 = __expf(e0.y);
            const float s2 = __expf(e0.z), s3 = __expf(e0.w);
            const float u0 = __expf(e1.x), u1 = __expf(e1.y);
            const float u2 = __expf(e1.z), u3 = __expf(e1.w);
            c00[0] *= s0; c00[1] *= s1; c00[2] *= s2; c00[3] *= s3;
            c01[0] *= s0; c01[1] *= s1; c01[2] *= s2; c01[3] *= s3;
            c10[0] *= u0; c10[1] *= u1; c10[2] *= u2; c10[3] *= u3;
            c11[0] *= u0; c11[1] *= u1; c11[2] *= u2; c11[3] *= u3;

            if ((applied & 7) == 7) {             // element-(0,0) renorm
                const float cn = __uint_as_float(
                    __builtin_amdgcn_readfirstlane(__float_as_uint(c00[0])));
                const float rs = 1.0f / cn;
#pragma unroll
                for (int r = 0; r < 4; ++r) {
                    c00[r] *= rs; c01[r] *= rs; c10[r] *= rs; c11[r] *= rs;
                }
                Slog += __logf(cn);
            }
            ++applied;

            // pack C -> next B (pi-order makes this the lane's own data)
            B0.u[0] = pack_trunc(c00[1], c00[0]);
            B0.u[1] = pack_trunc(c00[3], c00[2]);
            B0.u[2] = pack_trunc(c10[1], c10[0]);
            B0.u[3] = pack_trunc(c10[3], c10[2]);
            B1.u[0] = pack_trunc(c01[1], c01[0]);
            B1.u[1] = pack_trunc(c01[3], c01[2]);
            B1.u[2] = pack_trunc(c11[1], c11[0]);
            B1.u[3] = pack_trunc(c11[3], c11[2]);
        }
    };

    for (int i = 0; i < CHL; i += 2) {            // uniform 64 steps, unroll-2
        const int t = tbase + i;
        dostep(t, eA0, eA1);
        {
            const int tn = (t + 2 <= tmax) ? (t + 2) : tmax;
            eA0 = ypr0[(size_t)tn * 8]; eA1 = ypr1[(size_t)tn * 8];
        }
        dostep(t + 1, eB0, eB1);
        {
            const int tn = (t + 3 <= tmax) ? (t + 3) : tmax;
            eB0 = ypr0[(size_t)tn * 8]; eB1 = ypr1[(size_t)tn * 8];
        }
    }

    // ---- one-time LDS transpose: B frags -> col-major, then dump M^T row-major ----
    {
        unsigned* Nd = (unsigned*)Ncm;            // dword view, col stride 20
        *(uint2*)&Nd[n * 20 + q * 2]            = make_uint2(B0.u[0], B0.u[1]);  // col n, rows q*4..
        *(uint2*)&Nd[n * 20 + 8 + q * 2]        = make_uint2(B0.u[2], B0.u[3]);  // col n, rows 16+q*4..
        *(uint2*)&Nd[(16 + n) * 20 + q * 2]     = make_uint2(B1.u[0], B1.u[1]);
        *(uint2*)&Nd[(16 + n) * 20 + 8 + q * 2] = make_uint2(B1.u[2], B1.u[3]);
    }
    unsigned* md = wsMT + (size_t)blockIdx.x * 512;
    for (int idx = lane; idx < 512; idx += 64) {
        const int k = idx >> 4, d = idx & 15;
        const unsigned lo = Ncm[(2 * d) * 40 + k];
        const unsigned hi = Ncm[(2 * d + 1) * 40 + k];
        md[idx] = lo | (hi << 16);
    }
    if (lane == 0) {
        wsS[blockIdx.x]  = Slog + (float)applied * 3.46573590f;   // + applied*5*ln2
        wsSc[blockIdx.x] = sc;
    }
}

// ---------------- Phase 2: serial combine (LDS-staged) ----------------
__global__ __launch_bounds__(64) void crf_combine(
    const float*    __restrict__ y_pred,
    const unsigned* __restrict__ wsMT,
    const float*    __restrict__ wsS,
    const float*    __restrict__ wsSc,
    float*          __restrict__ out)
{
    __shared__ unsigned shA[16 * 32 * 20];        // 16 matrices, row stride 20 dwords
    __shared__ __align__(16) float sh_p[64];

    const int lane = threadIdx.x;
    const int half = lane >> 5;
    const int j    = lane & 31;
    const int seq  = blockIdx.x * 2 + half;

    const float* yp = y_pred + (size_t)seq * Tt * K32;

    // stage 16 matrices (2 seqs x 8 chunks), coalesced b128
    const uint4* src = (const uint4*)(wsMT + (size_t)blockIdx.x * 2 * NCH * 512);
    for (int g = lane; g < 2048; g += 64) {
        const uint4 v = src[g];
        const int fd  = g << 2;
        const int scm = fd >> 9;
        const int rem = fd & 511;
        const int k   = rem >> 4;
        const int d   = rem & 15;
        *(uint4*)&shA[scm * 640 + k * 20 + d] = v;
    }
    __syncthreads();

    const float a0 = yp[j];
    const float m0 = SWZ0(a0);
    float p = __expf(a0 - m0);
    float S = m0;
    float scs = 0.0f;
#pragma unroll
    for (int cc = 0; cc < NCH; ++cc) {
        S   += wsS[seq * NCH + cc];
        scs += wsSc[seq * NCH + cc];
    }

    const float4* e4 = (const float4*)&sh_p[half * K32];

    for (int cc = 0; cc < NCH; ++cc) {
        sh_p[lane] = p;
        const unsigned* row = &shA[(half * NCH + cc) * 640 + j * 20];  // M^T row j
        float acc = 0.0f, cn = 0.0f;
#pragma unroll
        for (int ib = 0; ib < 8; ++ib) {
            const float4 pv = e4[ib];
            if (ib == 0) cn = pv.x;
            const unsigned d0 = row[2 * ib];
            const unsigned d1 = row[2 * ib + 1];
            acc = fmaf(pv.x, bf2f(d0 & 0xFFFFu), acc);
            acc = fmaf(pv.y, bf2f(d0 >> 16),     acc);
            acc = fmaf(pv.z, bf2f(d1 & 0xFFFFu), acc);
            acc = fmaf(pv.w, bf2f(d1 >> 16),     acc);
        }
        const float r = 1.0f / cn;
        p = acc * r;
        S += __logf(cn);
    }

    float sp = p;
    sp += SWZX(sp, 1);
    sp += SWZX(sp, 2);
    sp += SWZX(sp, 4);
    sp += SWZX(sp, 8);
    sp += SWZX(sp, 16);

    if (j == 0) {
        out[seq] = S + __logf(sp) - scs;
    }
}

extern "C" void kernel_launch(void* const* d_in, const int* in_sizes, int n_in,
                              void* d_out, int out_size, void* d_ws, size_t ws_size,
                              hipStream_t stream) {
    const int*   labels = (const int*)  d_in[0];
    const float* y_pred = (const float*)d_in[1];
    const float* trans  = (const float*)d_in[2];
    const float* mask   = (const float*)d_in[3];
    float* out = (float*)d_out;

    // workspace carve: M^T (16 MB) | S (32 KB) | Sc (32 KB)
    unsigned* wsMT = (unsigned*)d_ws;
    float* wsS  = (float*)((char*)d_ws + (size_t)1024 * NCH * 512 * 4);
    float* wsSc = wsS + 1024 * NCH;

    crf_chunk<<<1024 * NCH, 64, 0, stream>>>(labels, y_pred, trans, mask, wsMT, wsS, wsSc);
    crf_combine<<<512, 64, 0, stream>>>(y_pred, wsMT, wsS, wsSc, out);
}